// Round 14
// baseline (124.807 us; speedup 1.0000x reference)
//
#include <hip/hip_runtime.h>
#include <math.h>

#define BN 8192
#define CN 1000
#define DN 128
#define INVT (1.0f/0.3f)
#define EXP2C 4.80898346962988f   // (1/0.3) * log2(e)

typedef __bf16 bf16x8 __attribute__((ext_vector_type(8)));
typedef float  f32x4  __attribute__((ext_vector_type(4)));

// ws layout in floats
#define F_FEATN  0          // 8192*128
#define F_MEANSN 1048576    // 1000*128
#define F_XX     1176576    // 8192
#define F_YY     1184768    // 1000
#define F_DIAG   1185768    // 8192
#define F_FEATB  1193960    // 8192*128 bf16
#define F_MEANSB 1718248    // 1024*128 bf16 (raw, zero-padded)
#define F_PL     1808360    // 16*8192 CE partial sums
#define F_BOT    1939432    // 8192   -- zeroed region start
#define F_CNT    1947624    // 1000 ints
#define F_CSUM   1948624    // 1000*128
#define F_RED    2076624    // 4 loss accumulators (sp, nv, ce, mg)
#define NZERO    (8192 + 1000 + 128000 + 4)   // floats to zero from F_BOT

// norm_all block ranges
#define NB_FEAT  2048
#define NB_MEANS 256
#define NB_ZERO  64

// mega-kernel block ranges: 64-row blocks, 2x16KB half-tile ping-pong, (256,3)
#define NB_SCL  576   // a=64-row block (128), strips of <=8 j-tiles, J>=A=a/2
#define NB_NSD  1024  // 128 i-blocks(64 rows) x 8 j-tiles(128 cols)
#define NB_CSUM 512

__device__ __forceinline__ void async16(const void* g, void* s) {
    __builtin_amdgcn_global_load_lds(
        (const __attribute__((address_space(1))) void*)g,
        (__attribute__((address_space(3))) void*)s, 16, 0, 0);
}

// -------- fused prep: feat-normalize | means-normalize | zero accumulators --------
__global__ void norm_all(const float* __restrict__ feat, const float* __restrict__ means,
                         float* __restrict__ featn, float* __restrict__ meansn,
                         float* __restrict__ xx, float* __restrict__ yy,
                         __bf16* __restrict__ featb, __bf16* __restrict__ meansb,
                         float* __restrict__ diag, const int* __restrict__ labels,
                         int* __restrict__ counts, float* __restrict__ zbase) {
    int bx = blockIdx.x;
    int lane = threadIdx.x & 63;
    if (bx < NB_FEAT) {
        int row = bx * 4 + (threadIdx.x >> 6);
        float f0 = feat[row * DN + lane];
        float f1 = feat[row * DN + 64 + lane];
        float ss = f0 * f0 + f1 * f1;
        #pragma unroll
        for (int o = 32; o > 0; o >>= 1) ss += __shfl_xor(ss, o);
        float inv = 1.0f / fmaxf(sqrtf(ss), 1e-12f);
        float n0 = f0 * inv, n1 = f1 * inv;
        featn[row * DN + lane] = n0;
        featn[row * DN + 64 + lane] = n1;
        __bf16 b0 = (__bf16)n0, b1 = (__bf16)n1;
        featb[row * DN + lane] = b0;
        featb[row * DN + 64 + lane] = b1;
        float fb0 = (float)b0, fb1 = (float)b1;
        float sb = fb0 * fb0 + fb1 * fb1;
        #pragma unroll
        for (int o = 32; o > 0; o >>= 1) sb += __shfl_xor(sb, o);
        if (lane == 0) {
            diag[row] = sb;
            xx[row] = ss * inv * inv;
            atomicAdd(&counts[labels[row]], 1);   // counts pre-zeroed by the memset
        }
    } else if (bx < NB_FEAT + NB_MEANS) {
        int row = (bx - NB_FEAT) * 4 + (threadIdx.x >> 6);   // 0..1023
        float f0 = (row < CN) ? means[row * DN + lane] : 0.f;
        float f1 = (row < CN) ? means[row * DN + 64 + lane] : 0.f;
        meansb[row * DN + lane] = (__bf16)f0;
        meansb[row * DN + 64 + lane] = (__bf16)f1;
        if (row >= CN) return;
        float ss = f0 * f0 + f1 * f1;
        #pragma unroll
        for (int o = 32; o > 0; o >>= 1) ss += __shfl_xor(ss, o);
        float inv = 1.0f / fmaxf(sqrtf(ss), 1e-12f);
        meansn[row * DN + lane] = f0 * inv;
        meansn[row * DN + 64 + lane] = f1 * inv;
        if (lane == 0) yy[row] = ss;
    } else {
        // zero bottom + csum + red (counts excluded: owned by the pre-memset,
        // since this kernel's feat blocks atomically increment them concurrently)
        int b2 = bx - NB_FEAT - NB_MEANS;
        for (int idx = b2 * 256 + (int)threadIdx.x; idx < NZERO; idx += NB_ZERO * 256) {
            if (idx < 8192 || idx >= 9192) zbase[idx] = 0.f;
        }
    }
}

// -------- mega kernel: 2x16KB half-tile ping-pong, vmcnt(4) pipeline, 3 blocks/CU --------
// [0,576) scl-tri | [576,1600) nsd | [1600,2112) csum
__global__ __launch_bounds__(256, 3) void mega_kernel(
        const __bf16* __restrict__ featb, const __bf16* __restrict__ meansb,
        const float* __restrict__ featn, const int* __restrict__ labels,
        const float* __restrict__ xx, const float* __restrict__ yy,
        float* __restrict__ out, float* __restrict__ pl,
        float* __restrict__ bottom, float* __restrict__ csum) {
    __shared__ uint4 sh[2][1024];       // two 64-row x 128-col bf16 half-tiles
    int bx = blockIdx.x;
    int tid = threadIdx.x;
    int lane = tid & 63, w = tid >> 6;
    int q = lane >> 4, l15 = lane & 15;
    int wrow = (w >> 1) * 32;

    // async-stage one 64x128 half-tile (16 KB) into sh[buf]; 4 DMAs per lane.
    // XOR swizzle folded into per-lane SOURCE chunk; r = row within half.
    auto stage64 = [&](const uint4* src, int row0, int buf) {
        #pragma unroll
        for (int s = 0; s < 4; s++) {
            int rb = w * 16 + s * 4;
            int r = rb + q;
            async16(&src[(size_t)(row0 + r) * 16 + (l15 ^ (r & 7))], &sh[buf][rb * 16]);
        }
    };

    if (bx < NB_SCL) {
        // ---- SCL: 64-row block a (A = a>>1), strip of <=8 128-col j-tiles J>=A,
        //      processed as 2*len 64-col... (64 j-rows) half-tiles, ping-ponged ----
        int rem = bx, a = 0;
        while (true) { int ns = (64 - (a >> 1) + 7) >> 3; if (rem < ns) break; rem -= ns; ++a; }
        int A = a >> 1;
        int J0 = A + rem * 8;
        int len = min(8, 64 - J0);
        int i0 = a * 64;
        const uint4* fv = (const uint4*)featb;
        int wc = (w & 1) * 32;

        bf16x8 af[2][4];
        #pragma unroll
        for (int ii = 0; ii < 2; ii++) {
            size_t r = (size_t)(i0 + wrow + ii * 16 + l15) * 16;
            #pragma unroll
            for (int kk = 0; kk < 4; kk++)
                af[ii][kk] = *(const bf16x8*)&fv[r + kk * 4 + q];
        }
        float bs[2][4] = {};

        int nh = 2 * len;                       // nh >= 2 always
        stage64(fv, J0 * 128, 0);
        stage64(fv, J0 * 128 + 64, 1);

        for (int h = 0; h < nh; h++) {
            // wait for half h's 4 DMAs; half h+1's stay in flight
            if (h + 1 < nh) asm volatile("s_waitcnt vmcnt(4)" ::: "memory");
            else            asm volatile("s_waitcnt vmcnt(0)" ::: "memory");
            __builtin_amdgcn_s_barrier();
            const uint4* B = sh[h & 1];

            f32x4 acc[2][2];
            #pragma unroll
            for (int ii = 0; ii < 2; ii++)
                #pragma unroll
                for (int jj = 0; jj < 2; jj++) acc[ii][jj] = (f32x4){0.f, 0.f, 0.f, 0.f};
            #pragma unroll
            for (int kk = 0; kk < 4; kk++) {
                bf16x8 bfv[2];
                #pragma unroll
                for (int jj = 0; jj < 2; jj++) {
                    int r = wc + jj * 16 + l15;
                    bfv[jj] = *(const bf16x8*)&B[r * 16 + ((kk * 4 + q) ^ (r & 7))];
                }
                #pragma unroll
                for (int ii = 0; ii < 2; ii++)
                    #pragma unroll
                    for (int jj = 0; jj < 2; jj++)
                        acc[ii][jj] = __builtin_amdgcn_mfma_f32_16x16x32_bf16(
                            af[ii][kk], bfv[jj], acc[ii][jj], 0, 0, 0);
            }

            float cp[2] = {0.f, 0.f};
            #pragma unroll
            for (int ii = 0; ii < 2; ii++)
                #pragma unroll
                for (int jj = 0; jj < 2; jj++)
                    #pragma unroll
                    for (int r4 = 0; r4 < 4; r4++) {
                        float e = exp2f(acc[ii][jj][r4] * EXP2C);
                        bs[ii][r4] += e;
                        cp[jj] += e;
                    }
            if (J0 + (h >> 1) != A) {   // mirror column sums (skip diagonal tile)
                #pragma unroll
                for (int jj = 0; jj < 2; jj++) {
                    float c = cp[jj];
                    c += __shfl_xor(c, 16);
                    c += __shfl_xor(c, 32);
                    if (lane < 16)
                        atomicAdd(&bottom[J0 * 128 + h * 64 + wc + jj * 16 + l15], c);
                }
            }
            __builtin_amdgcn_s_barrier();   // all waves done reading sh[h&1]
            if (h + 2 < nh) stage64(fv, J0 * 128 + (h + 2) * 64, h & 1);
        }
        int ibase = i0 + wrow + q * 4;
        #pragma unroll
        for (int ii = 0; ii < 2; ii++)
            #pragma unroll
            for (int r4 = 0; r4 < 4; r4++) {
                float b = bs[ii][r4];
                #pragma unroll
                for (int o = 8; o > 0; o >>= 1) b += __shfl_xor(b, o);
                if (l15 == 0) atomicAdd(&bottom[ibase + ii * 16 + r4], b);
            }

    } else if (bx < NB_SCL + NB_NSD) {
        // ---- NSD: 64 rows x 128 cols; B tile staged as two halves (sh[0]/sh[1]),
        //      wave w reads half (w&1). Bounded logits -> direct exp-sum ----
        int b = bx - NB_SCL;
        int i0 = (b >> 3) * 64, j0 = (b & 7) * 128;
        const uint4* fv = (const uint4*)featb;
        const uint4* mv = (const uint4*)meansb;
        stage64(mv, j0, 0);
        stage64(mv, j0 + 64, 1);

        int wcol = (w & 1) * 64;
        bf16x8 af[2][4];
        #pragma unroll
        for (int ii = 0; ii < 2; ii++) {
            size_t r = (size_t)(i0 + wrow + ii * 16 + l15) * 16;
            #pragma unroll
            for (int kk = 0; kk < 4; kk++)
                af[ii][kk] = *(const bf16x8*)&fv[r + kk * 4 + q];
        }
        __syncthreads();                // drains DMAs + barrier
        const uint4* B = sh[w & 1];

        f32x4 acc[2][4];
        #pragma unroll
        for (int ii = 0; ii < 2; ii++)
            #pragma unroll
            for (int jj = 0; jj < 4; jj++) acc[ii][jj] = (f32x4){0.f, 0.f, 0.f, 0.f};
        #pragma unroll
        for (int kk = 0; kk < 4; kk++) {
            bf16x8 bfv[4];
            #pragma unroll
            for (int jj = 0; jj < 4; jj++) {
                int rl = jj * 16 + l15;          // row within the half (0..63)
                bfv[jj] = *(const bf16x8*)&B[rl * 16 + ((kk * 4 + q) ^ (rl & 7))];
            }
            #pragma unroll
            for (int ii = 0; ii < 2; ii++)
                #pragma unroll
                for (int jj = 0; jj < 4; jj++)
                    acc[ii][jj] = __builtin_amdgcn_mfma_f32_16x16x32_bf16(
                        af[ii][kk], bfv[jj], acc[ii][jj], 0, 0, 0);
        }
        int jg[4]; float yv[4];
        #pragma unroll
        for (int jj = 0; jj < 4; jj++) {
            jg[jj] = j0 + wcol + jj * 16 + l15;
            yv[jj] = (jg[jj] < CN) ? yy[jg[jj]] : 0.f;
        }
        int pslot = ((b & 7) * 2 + (w & 1)) * BN;
        int ibase = i0 + wrow + q * 4;
        #pragma unroll
        for (int ii = 0; ii < 2; ii++) {
            int rbase = ibase + ii * 16;
            float4 xv = ((const float4*)xx)[rbase >> 2];
            int4 lv = ((const int4*)labels)[rbase >> 2];
            float xa[4] = {xv.x, xv.y, xv.z, xv.w};
            int la[4] = {lv.x, lv.y, lv.z, lv.w};
            #pragma unroll
            for (int r4 = 0; r4 < 4; r4++) {
                int ig = rbase + r4;
                float s = 0.f;
                #pragma unroll
                for (int jj = 0; jj < 4; jj++) {
                    float v = -0.5f * (xa[r4] - 2.f * acc[ii][jj][r4] + yv[jj]);
                    bool ok = (jg[jj] < CN);
                    if (ok) out[(size_t)ig * CN + jg[jj]] = v;
                    float l = (jg[jj] == la[r4]) ? 1.5f * v : v;
                    s += ok ? __expf(l) : 0.f;
                }
                #pragma unroll
                for (int o = 8; o > 0; o >>= 1) s += __shfl_xor(s, o);
                if (l15 == 0) pl[pslot + ig] = s;
            }
        }

    } else {
        // ---- csum: class-sum vectors via atomics ----
        int b2 = bx - NB_SCL - NB_NSD;
        for (int idx = b2 * 256 + tid; idx < BN * DN; idx += NB_CSUM * 256) {
            int row = idx >> 7, d = idx & 127;
            atomicAdd(&csum[labels[row] * DN + d], featn[idx]);
        }
    }
}

// -------- fused per-row epilogue + full loss reduction (512 blocks x 16 rows) --------
__global__ void cemp_kernel(const float* __restrict__ featn, const float* __restrict__ meansn,
        const float* __restrict__ csum, const int* __restrict__ labels,
        const float* __restrict__ pl, const float* __restrict__ out,
        const float* __restrict__ bottom, const int* __restrict__ counts,
        const float* __restrict__ diag, const float* __restrict__ xx,
        float* __restrict__ red) {
    int tid = threadIdx.x;
    int lane = tid & 63, w = tid >> 6;
    float a_sp = 0.f, a_nv = 0.f, a_ce = 0.f, a_mg = 0.f;
    for (int pass = 0; pass < 4; pass++) {
        int row = blockIdx.x * 16 + pass * 4 + w;
        int lab = labels[row];
        float f0 = featn[row * DN + lane],  f1 = featn[row * DN + 64 + lane];
        float m0 = meansn[lab * DN + lane], m1 = meansn[lab * DN + 64 + lane];
        float c0 = csum[lab * DN + lane],   c1 = csum[lab * DN + 64 + lane];
        float d0 = f0 - m0, d1 = f1 - m1;
        float ss = d0 * d0 + d1 * d1;
        float pp = f0 * c0 + f1 * c1;
        #pragma unroll
        for (int o = 32; o > 0; o >>= 1) {
            ss += __shfl_xor(ss, o);
            pp += __shfl_xor(pp, o);
        }
        if (lane == 0) {
            float S = 0.f;
            #pragma unroll
            for (int k = 0; k < 16; k++) S += pl[k * BN + row];
            a_ce += __logf(S) - 1.5f * out[(size_t)row * CN + lab];
            a_mg += ss;
            float bot = bottom[row] - __expf(diag[row] * INVT);  // exclude j==i
            float pv = (pp - xx[row]) * INVT;                    // exclude j==i
            int c = counts[lab] - 1;
            if (c > 0) {
                a_sp += pv / (float)c - __logf(bot);
                a_nv += 1.f;
            }
        }
    }
    __shared__ float r4[4][4];
    if (lane == 0) { r4[w][0] = a_sp; r4[w][1] = a_nv; r4[w][2] = a_ce; r4[w][3] = a_mg; }
    __syncthreads();
    if (tid < 4)
        atomicAdd(&red[tid], r4[0][tid] + r4[1][tid] + r4[2][tid] + r4[3][tid]);
}

__global__ void final_fin(const float* __restrict__ red, float* __restrict__ loss_out) {
    float SP = red[0], NV = red[1], CE = red[2], MG = red[3];
    float scl = -SP / fmaxf(NV, 1.f);
    loss_out[0] = 0.9f * (CE / (float)BN) + 0.1f * scl + 0.5f * (MG / (2.f * (float)BN));
}

extern "C" void kernel_launch(void* const* d_in, const int* in_sizes, int n_in,
                              void* d_out, int out_size, void* d_ws, size_t ws_size,
                              hipStream_t stream) {
    const float* feat   = (const float*)d_in[0];
    const int*   labels = (const int*)d_in[1];
    const float* means  = (const float*)d_in[2];
    float* out = (float*)d_out;
    float* ws  = (float*)d_ws;

    float*  featn  = ws + F_FEATN;
    float*  meansn = ws + F_MEANSN;
    float*  xx     = ws + F_XX;
    float*  yy     = ws + F_YY;
    float*  diag   = ws + F_DIAG;
    __bf16* featb  = (__bf16*)(ws + F_FEATB);
    __bf16* meansb = (__bf16*)(ws + F_MEANSB);
    float*  pl     = ws + F_PL;
    float*  bottom = ws + F_BOT;
    int*    counts = (int*)(ws + F_CNT);
    float*  csum   = ws + F_CSUM;
    float*  red    = ws + F_RED;

    // counts must be zero BEFORE norm_all's histogram atomics (inter-block order
    // within a kernel is undefined); bottom/csum/red are zeroed by norm_all's
    // zero-range (only read by mega, which launches after).
    hipMemsetAsync(counts, 0, 1000 * sizeof(int), stream);

    norm_all<<<NB_FEAT + NB_MEANS + NB_ZERO, 256, 0, stream>>>(
        feat, means, featn, meansn, xx, yy, featb, meansb, diag, labels, counts,
        ws + F_BOT);
    mega_kernel<<<NB_SCL + NB_NSD + NB_CSUM, 256, 0, stream>>>(
        featb, meansb, featn, labels, xx, yy, out, pl, bottom, csum);
    cemp_kernel<<<512, 256, 0, stream>>>(featn, meansn, csum, labels, pl, out,
                                         bottom, counts, diag, xx, red);
    final_fin<<<1, 1, 0, stream>>>(red, out + (size_t)BN * CN);
}